// Round 7
// baseline (1913.016 us; speedup 1.0000x reference)
//
// round 6: phase-sliced gather — 6 x 3.2MB slices kept L2-resident; out-of-slice
// lanes gather the zero pad row (zeros are MFMA-neutral); nbr/residual loads NT.
#include <hip/hip_runtime.h>
#include <hip/hip_bf16.h>

#define NV 300000
#define CH 32
#define KK 27
#define KP 28            // padded k-slices (slice 27 = zeros)
#define NPH 6
#define SLICE 51200      // rows per phase slice; 6*51200 = 307200 >= NV+1

typedef __attribute__((ext_vector_type(8))) short bf16x8;
typedef __attribute__((ext_vector_type(4))) float f32x4;

// ws layout (bytes)
#define XB_OFF   0u
#define HB_OFF   19200128u            // (NV+1)*CH*2 = 19200064, padded
#define W0T_OFF  38400256u            // KP*CH*CH*2 = 57344
#define W1T_OFF  38457600u

__device__ __forceinline__ unsigned short f2b(float f) {
    unsigned int u = __builtin_bit_cast(unsigned int, f);
    unsigned int r = (u + 0x7FFFu + ((u >> 16) & 1u)) >> 16;
    return (unsigned short)r;
}

// --- prep: x -> bf16 (+pad row), zero h pad row, transpose weights to [k][d][c] bf16 (28 slices)
__global__ __launch_bounds__(256) void prep_kernel(
    const float* __restrict__ x,
    const float* __restrict__ w0,
    const float* __restrict__ w1,
    unsigned short* __restrict__ xb,
    unsigned short* __restrict__ hb,
    unsigned short* __restrict__ w0t,
    unsigned short* __restrict__ w1t)
{
    const int NX = NV * CH / 8;  // 1,200,000
    int tid = blockIdx.x * blockDim.x + threadIdx.x;
    if (tid < NX) {
        int base = tid * 8;
        const float4* p = reinterpret_cast<const float4*>(x + base);
        float4 a = p[0], b = p[1];
        union { unsigned short u[8]; bf16x8 v; } pk;
        pk.u[0] = f2b(a.x); pk.u[1] = f2b(a.y); pk.u[2] = f2b(a.z); pk.u[3] = f2b(a.w);
        pk.u[4] = f2b(b.x); pk.u[5] = f2b(b.y); pk.u[6] = f2b(b.z); pk.u[7] = f2b(b.w);
        *reinterpret_cast<bf16x8*>(xb + base) = pk.v;
        return;
    }
    int t = tid - NX;
    if (t < 4) {
        union { unsigned short u[8]; bf16x8 v; } z;
        for (int j = 0; j < 8; ++j) z.u[j] = 0;
        *reinterpret_cast<bf16x8*>(xb + NV * CH + t * 8) = z.v;
        return;
    }
    t -= 4;
    if (t < 4) {
        union { unsigned short u[8]; bf16x8 v; } z;
        for (int j = 0; j < 8; ++j) z.u[j] = 0;
        *reinterpret_cast<bf16x8*>(hb + NV * CH + t * 8) = z.v;
        return;
    }
    t -= 4;
    const int WELEM = KP * CH * CH;  // 28672
    if (t < 2 * WELEM) {
        int which = t >= WELEM;
        int e = t - which * WELEM;
        int k = e >> 10;
        int rem = e & 1023;
        int d = rem >> 5;
        int c = rem & 31;
        unsigned short* o = which ? w1t : w0t;
        if (k == KK) {
            o[e] = 0;
        } else {
            const float* w = which ? w1 : w0;
            o[e] = f2b(w[k * 1024 + c * 32 + d]);
        }
    }
}

// --- conv layer: 32 rows/wave, phase-sliced gathers, mfma 16x16x32 bf16
template <bool FIRST>
__global__ __launch_bounds__(256) void conv_kernel(
    const unsigned short* __restrict__ in_b,  // (NV+1)*CH bf16
    const int* __restrict__ nbr,              // KK*NV
    const unsigned short* __restrict__ wt,    // KP*CH*CH bf16, slice 27 = 0
    const float* __restrict__ bias,           // CH
    const float* __restrict__ xres,           // NV*CH f32 (layer2) or null
    unsigned short* __restrict__ out_b,       // layer1 out (bf16)
    float* __restrict__ out_f)                // layer2 out (f32)
{
    const int wave = (blockIdx.x * blockDim.x + threadIdx.x) >> 6;
    if (wave >= NV / 32) return;   // 9375 waves
    const int lane = threadIdx.x & 63;
    const int r = lane & 15;
    const int g = lane >> 4;
    const int row0 = wave * 32;
    const int i0 = row0 + r;
    const int i1 = row0 + 16 + r;

    f32x4 acc00 = {0.f, 0.f, 0.f, 0.f};
    f32x4 acc01 = {0.f, 0.f, 0.f, 0.f};
    f32x4 acc10 = {0.f, 0.f, 0.f, 0.f};
    f32x4 acc11 = {0.f, 0.f, 0.f, 0.f};

    const unsigned short* wt_r0 = wt + r * CH + g * 8;
    const unsigned short* wt_r1 = wt + (r + 16) * CH + g * 8;

    for (int ph = 0; ph < NPH; ++ph) {
        const unsigned int lo = ph * SLICE;
#pragma unroll
        for (int kb = 0; kb < KP; kb += 4) {
            int idx0[4], idx1[4];
#pragma unroll
            for (int j = 0; j < 4; ++j) {
                int kk = kb + j;
                int ks = kk < KK ? kk : KK - 1;   // k=27 reuses 26 (B slice is zero)
                idx0[j] = __builtin_nontemporal_load(nbr + ks * NV + i0);
                idx1[j] = __builtin_nontemporal_load(nbr + ks * NV + i1);
            }
            // redirect out-of-slice rows to the zero pad row (row NV)
            int off0[4], off1[4];
#pragma unroll
            for (int j = 0; j < 4; ++j) {
                off0[j] = ((unsigned int)(idx0[j] - (int)lo) < SLICE) ? idx0[j] : NV;
                off1[j] = ((unsigned int)(idx1[j] - (int)lo) < SLICE) ? idx1[j] : NV;
            }
            bf16x8 a0[4], a1[4];
#pragma unroll
            for (int j = 0; j < 4; ++j) {
                a0[j] = *reinterpret_cast<const bf16x8*>(in_b + (size_t)off0[j] * CH + g * 8);
                a1[j] = *reinterpret_cast<const bf16x8*>(in_b + (size_t)off1[j] * CH + g * 8);
            }
#pragma unroll
            for (int j = 0; j < 4; ++j) {
                int kk = kb + j;
                bf16x8 b0 = *reinterpret_cast<const bf16x8*>(wt_r0 + kk * 1024);
                bf16x8 b1 = *reinterpret_cast<const bf16x8*>(wt_r1 + kk * 1024);
                acc00 = __builtin_amdgcn_mfma_f32_16x16x32_bf16(a0[j], b0, acc00, 0, 0, 0);
                acc10 = __builtin_amdgcn_mfma_f32_16x16x32_bf16(a1[j], b0, acc10, 0, 0, 0);
                acc01 = __builtin_amdgcn_mfma_f32_16x16x32_bf16(a0[j], b1, acc01, 0, 0, 0);
                acc11 = __builtin_amdgcn_mfma_f32_16x16x32_bf16(a1[j], b1, acc11, 0, 0, 0);
            }
        }
    }

    const float bs0 = bias[r];
    const float bs1 = bias[r + 16];
#pragma unroll
    for (int j = 0; j < 4; ++j) {
        int ra = row0 + g * 4 + j;
        int rb = ra + 16;
        float v00 = acc00[j] + bs0;
        float v01 = acc01[j] + bs1;
        float v10 = acc10[j] + bs0;
        float v11 = acc11[j] + bs1;
        if (FIRST) {
            out_b[ra * CH + r]      = f2b(fmaxf(v00, 0.f));
            out_b[ra * CH + r + 16] = f2b(fmaxf(v01, 0.f));
            out_b[rb * CH + r]      = f2b(fmaxf(v10, 0.f));
            out_b[rb * CH + r + 16] = f2b(fmaxf(v11, 0.f));
        } else {
            float r00 = __builtin_nontemporal_load(xres + (size_t)ra * CH + r);
            float r01 = __builtin_nontemporal_load(xres + (size_t)ra * CH + r + 16);
            float r10 = __builtin_nontemporal_load(xres + (size_t)rb * CH + r);
            float r11 = __builtin_nontemporal_load(xres + (size_t)rb * CH + r + 16);
            __builtin_nontemporal_store(v00 + r00, out_f + (size_t)ra * CH + r);
            __builtin_nontemporal_store(v01 + r01, out_f + (size_t)ra * CH + r + 16);
            __builtin_nontemporal_store(v10 + r10, out_f + (size_t)rb * CH + r);
            __builtin_nontemporal_store(v11 + r11, out_f + (size_t)rb * CH + r + 16);
        }
    }
}

extern "C" void kernel_launch(void* const* d_in, const int* in_sizes, int n_in,
                              void* d_out, int out_size, void* d_ws, size_t ws_size,
                              hipStream_t stream) {
    const float* x   = (const float*)d_in[0];
    const int* nbr   = (const int*)d_in[1];
    const float* w0  = (const float*)d_in[2];
    const float* b0  = (const float*)d_in[3];
    const float* w1  = (const float*)d_in[4];
    const float* b1  = (const float*)d_in[5];
    float* out = (float*)d_out;

    char* ws = (char*)d_ws;
    unsigned short* xb  = (unsigned short*)(ws + XB_OFF);
    unsigned short* hb  = (unsigned short*)(ws + HB_OFF);
    unsigned short* w0t = (unsigned short*)(ws + W0T_OFF);
    unsigned short* w1t = (unsigned short*)(ws + W1T_OFF);

    // prep
    {
        int total = NV * CH / 8 + 8 + 2 * KP * CH * CH;  // 1,257,352
        int blocks = (total + 255) / 256;
        prep_kernel<<<blocks, 256, 0, stream>>>(x, w0, w1, xb, hb, w0t, w1t);
    }
    // conv layers: one wave per 32 rows
    int threads = (NV / 32) * 64;        // 600,000
    int blocks = (threads + 255) / 256;  // 2344
    conv_kernel<true><<<blocks, 256, 0, stream>>>(xb, nbr, w0t, b0, nullptr, hb, nullptr);
    conv_kernel<false><<<blocks, 256, 0, stream>>>(hb, nbr, w1t, b1, x, nullptr, out);
}

// Round 9
// 1572.211 us; speedup vs baseline: 1.2168x; 1.2168x over previous
//
// round 8: cooperative phase-sliced conv WITH return-code check + r5 fallback.
// If coop launch is rejected, fall back to the proven flat kernel (130us/layer).
#include <hip/hip_runtime.h>
#include <hip/hip_cooperative_groups.h>
#include <hip/hip_bf16.h>

namespace cg = cooperative_groups;

#define NV 300000
#define CH 32
#define KK 27
#define KP 28              // padded k-slices (slice 27 = zeros)
#define NPH 6
#define SLICE_ROWS 50000   // 6*50000 = 300000; pad row NV never in-slice
#define RPW 80             // rows per wave (5 tiles of 16)
#define RPB 320            // rows per block (4 waves)
#define NBLK 938           // ceil(300000/320)

typedef __attribute__((ext_vector_type(8))) short bf16x8;
typedef __attribute__((ext_vector_type(4))) float f32x4;

// ws layout (bytes)
#define XB_OFF   0u
#define HB_OFF   19200128u            // (NV+1)*CH*2 = 19200064, padded
#define W0T_OFF  38400256u            // KP*CH*CH*2 = 57344
#define W1T_OFF  38457600u

__device__ __forceinline__ unsigned short f2b(float f) {
    unsigned int u = __builtin_bit_cast(unsigned int, f);
    unsigned int r = (u + 0x7FFFu + ((u >> 16) & 1u)) >> 16;
    return (unsigned short)r;
}

// --- prep: x -> bf16 (+pad row), zero h pad row, weights -> [k][d][c] bf16 (28 slices)
__global__ __launch_bounds__(256) void prep_kernel(
    const float* __restrict__ x,
    const float* __restrict__ w0,
    const float* __restrict__ w1,
    unsigned short* __restrict__ xb,
    unsigned short* __restrict__ hb,
    unsigned short* __restrict__ w0t,
    unsigned short* __restrict__ w1t)
{
    const int NX = NV * CH / 8;  // 1,200,000
    int tid = blockIdx.x * blockDim.x + threadIdx.x;
    if (tid < NX) {
        int base = tid * 8;
        const float4* p = reinterpret_cast<const float4*>(x + base);
        float4 a = p[0], b = p[1];
        union { unsigned short u[8]; bf16x8 v; } pk;
        pk.u[0] = f2b(a.x); pk.u[1] = f2b(a.y); pk.u[2] = f2b(a.z); pk.u[3] = f2b(a.w);
        pk.u[4] = f2b(b.x); pk.u[5] = f2b(b.y); pk.u[6] = f2b(b.z); pk.u[7] = f2b(b.w);
        *reinterpret_cast<bf16x8*>(xb + base) = pk.v;
        return;
    }
    int t = tid - NX;
    if (t < 4) {
        union { unsigned short u[8]; bf16x8 v; } z;
        for (int j = 0; j < 8; ++j) z.u[j] = 0;
        *reinterpret_cast<bf16x8*>(xb + NV * CH + t * 8) = z.v;
        return;
    }
    t -= 4;
    if (t < 4) {
        union { unsigned short u[8]; bf16x8 v; } z;
        for (int j = 0; j < 8; ++j) z.u[j] = 0;
        *reinterpret_cast<bf16x8*>(hb + NV * CH + t * 8) = z.v;
        return;
    }
    t -= 4;
    const int WELEM = KP * CH * CH;  // 28672
    if (t < 2 * WELEM) {
        int which = t >= WELEM;
        int e = t - which * WELEM;
        int k = e >> 10;
        int rem = e & 1023;
        int d = rem >> 5;
        int c = rem & 31;
        unsigned short* o = which ? w1t : w0t;
        if (k == KK) {
            o[e] = 0;
        } else {
            const float* w = which ? w1 : w0;
            o[e] = f2b(w[k * 1024 + c * 32 + d]);
        }
    }
}

// --- cooperative conv layer: 80 rows/wave, 6 grid-synced input-slice phases
template <bool FIRST>
__global__ __launch_bounds__(256, 4) void conv_coop(
    const unsigned short* __restrict__ in_b,
    const int* __restrict__ nbr,
    const unsigned short* __restrict__ wt,
    const float* __restrict__ bias,
    const float* __restrict__ xres,
    unsigned short* __restrict__ out_b,
    float* __restrict__ out_f)
{
    __shared__ int idx_lds[RPB][KP];          // 35840 B

    const int tid = threadIdx.x;
    const int brow0 = blockIdx.x * RPB;

    for (int e = tid; e < KK * RPB; e += 256) {
        int k = e / RPB;
        int rr = e - k * RPB;
        int grow = brow0 + rr;
        idx_lds[rr][k] = (grow < NV) ? nbr[k * NV + grow] : NV;
    }
    __syncthreads();
    for (int rr = tid; rr < RPB; rr += 256)
        idx_lds[rr][KK] = idx_lds[rr][KK - 1];   // k=27 reuses 26 (B slice is zero)
    __syncthreads();

    const int lane = tid & 63;
    const int wv   = tid >> 6;
    const int r = lane & 15;
    const int g = lane >> 4;
    const int wrow0 = wv * RPW;

    f32x4 accA0 = {0,0,0,0}, accB0 = {0,0,0,0};
    f32x4 accA1 = {0,0,0,0}, accB1 = {0,0,0,0};
    f32x4 accA2 = {0,0,0,0}, accB2 = {0,0,0,0};
    f32x4 accA3 = {0,0,0,0}, accB3 = {0,0,0,0};
    f32x4 accA4 = {0,0,0,0}, accB4 = {0,0,0,0};

    const unsigned short* wt_r0 = wt + r * CH + g * 8;
    const unsigned short* wt_r1 = wt + (r + 16) * CH + g * 8;

    cg::grid_group grid = cg::this_grid();

#define TILE_BODY(T) { \
        int idx = idx_lds[wrow0 + (T)*16 + r][k]; \
        int off = ((unsigned int)(idx - lo) < SLICE_ROWS) ? idx : NV; \
        bf16x8 a = *reinterpret_cast<const bf16x8*>(in_b + (size_t)off * CH + g * 8); \
        accA##T = __builtin_amdgcn_mfma_f32_16x16x32_bf16(a, b0, accA##T, 0, 0, 0); \
        accB##T = __builtin_amdgcn_mfma_f32_16x16x32_bf16(a, b1, accB##T, 0, 0, 0); }

    for (int ph = 0; ph < NPH; ++ph) {
        const unsigned int lo = (unsigned int)(ph * SLICE_ROWS);
#pragma unroll 2
        for (int k = 0; k < KP; ++k) {
            bf16x8 b0 = *reinterpret_cast<const bf16x8*>(wt_r0 + k * 1024);
            bf16x8 b1 = *reinterpret_cast<const bf16x8*>(wt_r1 + k * 1024);
            TILE_BODY(0)
            TILE_BODY(1)
            TILE_BODY(2)
            TILE_BODY(3)
            TILE_BODY(4)
        }
        if (ph != NPH - 1) grid.sync();
    }
#undef TILE_BODY

    const float bs0 = bias[r];
    const float bs1 = bias[r + 16];

#define EPILOGUE(T) { \
        _Pragma("unroll") \
        for (int j = 0; j < 4; ++j) { \
            int row = brow0 + wrow0 + (T)*16 + g * 4 + j; \
            if (row < NV) { \
                float v0 = accA##T[j] + bs0; \
                float v1 = accB##T[j] + bs1; \
                if (FIRST) { \
                    out_b[(size_t)row * CH + r]      = f2b(fmaxf(v0, 0.f)); \
                    out_b[(size_t)row * CH + r + 16] = f2b(fmaxf(v1, 0.f)); \
                } else { \
                    float r0 = __builtin_nontemporal_load(xres + (size_t)row * CH + r); \
                    float r1 = __builtin_nontemporal_load(xres + (size_t)row * CH + r + 16); \
                    __builtin_nontemporal_store(v0 + r0, out_f + (size_t)row * CH + r); \
                    __builtin_nontemporal_store(v1 + r1, out_f + (size_t)row * CH + r + 16); \
                } \
            } \
        } }

    EPILOGUE(0)
    EPILOGUE(1)
    EPILOGUE(2)
    EPILOGUE(3)
    EPILOGUE(4)
#undef EPILOGUE
}

// --- fallback: r5 flat kernel (32 rows/wave, batched gathers) — known-good 130us/layer
template <bool FIRST>
__global__ __launch_bounds__(256) void conv_flat(
    const unsigned short* __restrict__ in_b,
    const int* __restrict__ nbr,
    const unsigned short* __restrict__ wt,
    const float* __restrict__ bias,
    const float* __restrict__ xres,
    unsigned short* __restrict__ out_b,
    float* __restrict__ out_f)
{
    const int wave = (blockIdx.x * blockDim.x + threadIdx.x) >> 6;
    if (wave >= NV / 32) return;
    const int lane = threadIdx.x & 63;
    const int r = lane & 15;
    const int g = lane >> 4;
    const int row0 = wave * 32;
    const int i0 = row0 + r;
    const int i1 = row0 + 16 + r;

    f32x4 acc00 = {0,0,0,0}, acc01 = {0,0,0,0};
    f32x4 acc10 = {0,0,0,0}, acc11 = {0,0,0,0};

    const unsigned short* wt_r0 = wt + r * CH + g * 8;
    const unsigned short* wt_r1 = wt + (r + 16) * CH + g * 8;

#pragma unroll
    for (int kb = 0; kb < KP; kb += 4) {
        int idx0[4], idx1[4];
#pragma unroll
        for (int j = 0; j < 4; ++j) {
            int kk = kb + j;
            int ks = kk < KK ? kk : KK - 1;
            idx0[j] = nbr[ks * NV + i0];
            idx1[j] = nbr[ks * NV + i1];
        }
        bf16x8 a0[4], a1[4];
#pragma unroll
        for (int j = 0; j < 4; ++j) {
            a0[j] = *reinterpret_cast<const bf16x8*>(in_b + (size_t)idx0[j] * CH + g * 8);
            a1[j] = *reinterpret_cast<const bf16x8*>(in_b + (size_t)idx1[j] * CH + g * 8);
        }
#pragma unroll
        for (int j = 0; j < 4; ++j) {
            int kk = kb + j;
            bf16x8 b0 = *reinterpret_cast<const bf16x8*>(wt_r0 + kk * 1024);
            bf16x8 b1 = *reinterpret_cast<const bf16x8*>(wt_r1 + kk * 1024);
            acc00 = __builtin_amdgcn_mfma_f32_16x16x32_bf16(a0[j], b0, acc00, 0, 0, 0);
            acc10 = __builtin_amdgcn_mfma_f32_16x16x32_bf16(a1[j], b0, acc10, 0, 0, 0);
            acc01 = __builtin_amdgcn_mfma_f32_16x16x32_bf16(a0[j], b1, acc01, 0, 0, 0);
            acc11 = __builtin_amdgcn_mfma_f32_16x16x32_bf16(a1[j], b1, acc11, 0, 0, 0);
        }
    }

    const float bs0 = bias[r];
    const float bs1 = bias[r + 16];
#pragma unroll
    for (int j = 0; j < 4; ++j) {
        int ra = row0 + g * 4 + j;
        int rb = ra + 16;
        float v00 = acc00[j] + bs0;
        float v01 = acc01[j] + bs1;
        float v10 = acc10[j] + bs0;
        float v11 = acc11[j] + bs1;
        if (FIRST) {
            out_b[ra * CH + r]      = f2b(fmaxf(v00, 0.f));
            out_b[ra * CH + r + 16] = f2b(fmaxf(v01, 0.f));
            out_b[rb * CH + r]      = f2b(fmaxf(v10, 0.f));
            out_b[rb * CH + r + 16] = f2b(fmaxf(v11, 0.f));
        } else {
            out_f[ra * CH + r]      = v00 + xres[ra * CH + r];
            out_f[ra * CH + r + 16] = v01 + xres[ra * CH + r + 16];
            out_f[rb * CH + r]      = v10 + xres[rb * CH + r];
            out_f[rb * CH + r + 16] = v11 + xres[rb * CH + r + 16];
        }
    }
}

template <bool FIRST>
static void launch_layer(const unsigned short* in_b, const int* nbr,
                         const unsigned short* wt, const float* bias,
                         const float* xres, unsigned short* ob, float* of,
                         hipStream_t stream) {
    void* args[] = { (void*)&in_b, (void*)&nbr, (void*)&wt, (void*)&bias,
                     (void*)&xres, (void*)&ob, (void*)&of };
    hipError_t e = hipLaunchCooperativeKernel(
        reinterpret_cast<const void*>(&conv_coop<FIRST>),
        dim3(NBLK), dim3(256), args, 0, stream);
    if (e != hipSuccess) {
        (void)hipGetLastError();  // clear sticky error
        int threads = (NV / 32) * 64;
        int blocks = (threads + 255) / 256;
        conv_flat<FIRST><<<blocks, 256, 0, stream>>>(in_b, nbr, wt, bias, xres, ob, of);
    }
}

extern "C" void kernel_launch(void* const* d_in, const int* in_sizes, int n_in,
                              void* d_out, int out_size, void* d_ws, size_t ws_size,
                              hipStream_t stream) {
    const float* x   = (const float*)d_in[0];
    const int* nbr   = (const int*)d_in[1];
    const float* w0  = (const float*)d_in[2];
    const float* b0  = (const float*)d_in[3];
    const float* w1  = (const float*)d_in[4];
    const float* b1  = (const float*)d_in[5];
    float* out = (float*)d_out;

    char* ws = (char*)d_ws;
    unsigned short* xb  = (unsigned short*)(ws + XB_OFF);
    unsigned short* hb  = (unsigned short*)(ws + HB_OFF);
    unsigned short* w0t = (unsigned short*)(ws + W0T_OFF);
    unsigned short* w1t = (unsigned short*)(ws + W1T_OFF);

    {
        int total = NV * CH / 8 + 8 + 2 * KP * CH * CH;
        int blocks = (total + 255) / 256;
        prep_kernel<<<blocks, 256, 0, stream>>>(x, w0, w1, xb, hb, w0t, w1t);
    }

    launch_layer<true >(xb, nbr, w0t, b0, nullptr, hb, nullptr, stream);
    launch_layer<false>(hb, nbr, w1t, b1, x, nullptr, out, stream);
}

// Round 10
// 784.538 us; speedup vs baseline: 2.4384x; 2.0040x over previous
//
// round 9: persistent phase-sliced conv with FENCE-FREE soft barrier
// (atomic arrival counter + bounded s_sleep poll; no L2 flush, no coop launch).
// Alignment is perf-only: correctness never depends on the barrier.
#include <hip/hip_runtime.h>
#include <hip/hip_bf16.h>

#define NV 300000
#define CH 32
#define KK 27
#define KP 28              // padded k-slices (slice 27 = zeros)
#define NPH 6
#define SLICE_ROWS 50000   // 6*50000 = 300000; pad row NV never in-slice
#define RPW 80             // rows per wave (5 tiles of 16)
#define RPB 320            // rows per block (4 waves)
#define NBLK 938           // ceil(300000/320); all co-resident (938 <= 1024 slots)

typedef __attribute__((ext_vector_type(8))) short bf16x8;
typedef __attribute__((ext_vector_type(4))) float f32x4;

// ws layout (bytes)
#define XB_OFF   0u
#define HB_OFF   19200128u            // (NV+1)*CH*2 = 19200064, padded
#define W0T_OFF  38400256u            // KP*CH*CH*2 = 57344
#define W1T_OFF  38457600u
#define CTR_OFF  38514944u            // 2 layers x NPH ints

__device__ __forceinline__ unsigned short f2b(float f) {
    unsigned int u = __builtin_bit_cast(unsigned int, f);
    unsigned int r = (u + 0x7FFFu + ((u >> 16) & 1u)) >> 16;
    return (unsigned short)r;
}

// --- prep: x -> bf16 (+pad row), zero h pad row, weights -> [k][d][c] bf16, zero barriers
__global__ __launch_bounds__(256) void prep_kernel(
    const float* __restrict__ x,
    const float* __restrict__ w0,
    const float* __restrict__ w1,
    unsigned short* __restrict__ xb,
    unsigned short* __restrict__ hb,
    unsigned short* __restrict__ w0t,
    unsigned short* __restrict__ w1t,
    int* __restrict__ ctr)
{
    const int NX = NV * CH / 8;  // 1,200,000
    int tid = blockIdx.x * blockDim.x + threadIdx.x;
    if (tid < NX) {
        int base = tid * 8;
        const float4* p = reinterpret_cast<const float4*>(x + base);
        float4 a = p[0], b = p[1];
        union { unsigned short u[8]; bf16x8 v; } pk;
        pk.u[0] = f2b(a.x); pk.u[1] = f2b(a.y); pk.u[2] = f2b(a.z); pk.u[3] = f2b(a.w);
        pk.u[4] = f2b(b.x); pk.u[5] = f2b(b.y); pk.u[6] = f2b(b.z); pk.u[7] = f2b(b.w);
        *reinterpret_cast<bf16x8*>(xb + base) = pk.v;
        return;
    }
    int t = tid - NX;
    if (t < 4) {
        union { unsigned short u[8]; bf16x8 v; } z;
        for (int j = 0; j < 8; ++j) z.u[j] = 0;
        *reinterpret_cast<bf16x8*>(xb + NV * CH + t * 8) = z.v;
        return;
    }
    t -= 4;
    if (t < 4) {
        union { unsigned short u[8]; bf16x8 v; } z;
        for (int j = 0; j < 8; ++j) z.u[j] = 0;
        *reinterpret_cast<bf16x8*>(hb + NV * CH + t * 8) = z.v;
        return;
    }
    t -= 4;
    const int WELEM = KP * CH * CH;  // 28672
    if (t < 2 * WELEM) {
        int which = t >= WELEM;
        int e = t - which * WELEM;
        int k = e >> 10;
        int rem = e & 1023;
        int d = rem >> 5;
        int c = rem & 31;
        unsigned short* o = which ? w1t : w0t;
        if (k == KK) {
            o[e] = 0;
        } else {
            const float* w = which ? w1 : w0;
            o[e] = f2b(w[k * 1024 + c * 32 + d]);
        }
        return;
    }
    t -= 2 * WELEM;
    if (t < 2 * NPH) ctr[t] = 0;   // zero soft-barrier counters (every launch)
}

// --- persistent conv layer: 80 rows/wave, 6 input-slice phases, soft barrier between
template <bool FIRST>
__global__ __launch_bounds__(256, 4) void conv_phase(
    const unsigned short* __restrict__ in_b,
    const int* __restrict__ nbr,
    const unsigned short* __restrict__ wt,
    const float* __restrict__ bias,
    const float* __restrict__ xres,
    unsigned short* __restrict__ out_b,
    float* __restrict__ out_f,
    int* __restrict__ ctr)            // NPH arrival counters for this layer
{
    __shared__ int idx_lds[RPB][KP];          // 35840 B

    const int tid = threadIdx.x;
    const int brow0 = blockIdx.x * RPB;

    // stage this block's neighbor indices into LDS (once; coalesced per k)
    for (int e = tid; e < KK * RPB; e += 256) {
        int k = e / RPB;
        int rr = e - k * RPB;
        int grow = brow0 + rr;
        idx_lds[rr][k] = (grow < NV) ? __builtin_nontemporal_load(nbr + k * NV + grow) : NV;
    }
    __syncthreads();
    for (int rr = tid; rr < RPB; rr += 256)
        idx_lds[rr][KK] = idx_lds[rr][KK - 1];   // k=27 reuses 26 (B slice is zero)
    __syncthreads();

    const int lane = tid & 63;
    const int wv   = tid >> 6;
    const int r = lane & 15;
    const int g = lane >> 4;
    const int wrow0 = wv * RPW;

    f32x4 accA0 = {0,0,0,0}, accB0 = {0,0,0,0};
    f32x4 accA1 = {0,0,0,0}, accB1 = {0,0,0,0};
    f32x4 accA2 = {0,0,0,0}, accB2 = {0,0,0,0};
    f32x4 accA3 = {0,0,0,0}, accB3 = {0,0,0,0};
    f32x4 accA4 = {0,0,0,0}, accB4 = {0,0,0,0};

    const unsigned short* wt_r0 = wt + r * CH + g * 8;
    const unsigned short* wt_r1 = wt + (r + 16) * CH + g * 8;

#define TILE_BODY(T) { \
        int idx = idx_lds[wrow0 + (T)*16 + r][k]; \
        int off = ((unsigned int)(idx - lo) < SLICE_ROWS) ? idx : NV; \
        bf16x8 a = *reinterpret_cast<const bf16x8*>(in_b + (size_t)off * CH + g * 8); \
        accA##T = __builtin_amdgcn_mfma_f32_16x16x32_bf16(a, b0, accA##T, 0, 0, 0); \
        accB##T = __builtin_amdgcn_mfma_f32_16x16x32_bf16(a, b1, accB##T, 0, 0, 0); }

    for (int ph = 0; ph < NPH; ++ph) {
        const unsigned int lo = (unsigned int)(ph * SLICE_ROWS);
#pragma unroll 2
        for (int k = 0; k < KP; ++k) {
            bf16x8 b0 = *reinterpret_cast<const bf16x8*>(wt_r0 + k * 1024);
            bf16x8 b1 = *reinterpret_cast<const bf16x8*>(wt_r1 + k * 1024);
            TILE_BODY(0)
            TILE_BODY(1)
            TILE_BODY(2)
            TILE_BODY(3)
            TILE_BODY(4)
        }
        // fence-free soft barrier: aligns phases for L2 locality; no memory semantics
        // needed (in_b is read-only) -> no flush, bounded poll -> no deadlock.
        if (ph != NPH - 1) {
            __syncthreads();
            if (tid == 0) {
                __hip_atomic_fetch_add(&ctr[ph], 1, __ATOMIC_RELAXED,
                                       __HIP_MEMORY_SCOPE_AGENT);
                int polls = 0;
                while (__hip_atomic_load(&ctr[ph], __ATOMIC_RELAXED,
                                         __HIP_MEMORY_SCOPE_AGENT) < NBLK &&
                       polls < 500) {
                    __builtin_amdgcn_s_sleep(16);
                    ++polls;
                }
            }
            __syncthreads();
        }
    }
#undef TILE_BODY

    const float bs0 = bias[r];
    const float bs1 = bias[r + 16];

#define EPILOGUE(T) { \
        _Pragma("unroll") \
        for (int j = 0; j < 4; ++j) { \
            int row = brow0 + wrow0 + (T)*16 + g * 4 + j; \
            if (row < NV) { \
                float v0 = accA##T[j] + bs0; \
                float v1 = accB##T[j] + bs1; \
                if (FIRST) { \
                    out_b[(size_t)row * CH + r]      = f2b(fmaxf(v0, 0.f)); \
                    out_b[(size_t)row * CH + r + 16] = f2b(fmaxf(v1, 0.f)); \
                } else { \
                    float r0 = __builtin_nontemporal_load(xres + (size_t)row * CH + r); \
                    float r1 = __builtin_nontemporal_load(xres + (size_t)row * CH + r + 16); \
                    __builtin_nontemporal_store(v0 + r0, out_f + (size_t)row * CH + r); \
                    __builtin_nontemporal_store(v1 + r1, out_f + (size_t)row * CH + r + 16); \
                } \
            } \
        } }

    EPILOGUE(0)
    EPILOGUE(1)
    EPILOGUE(2)
    EPILOGUE(3)
    EPILOGUE(4)
#undef EPILOGUE
}

extern "C" void kernel_launch(void* const* d_in, const int* in_sizes, int n_in,
                              void* d_out, int out_size, void* d_ws, size_t ws_size,
                              hipStream_t stream) {
    const float* x   = (const float*)d_in[0];
    const int* nbr   = (const int*)d_in[1];
    const float* w0  = (const float*)d_in[2];
    const float* b0  = (const float*)d_in[3];
    const float* w1  = (const float*)d_in[4];
    const float* b1  = (const float*)d_in[5];
    float* out = (float*)d_out;

    char* ws = (char*)d_ws;
    unsigned short* xb  = (unsigned short*)(ws + XB_OFF);
    unsigned short* hb  = (unsigned short*)(ws + HB_OFF);
    unsigned short* w0t = (unsigned short*)(ws + W0T_OFF);
    unsigned short* w1t = (unsigned short*)(ws + W1T_OFF);
    int* ctr            = (int*)(ws + CTR_OFF);

    {
        int total = NV * CH / 8 + 8 + 2 * KP * CH * CH + 2 * NPH;
        int blocks = (total + 255) / 256;
        prep_kernel<<<blocks, 256, 0, stream>>>(x, w0, w1, xb, hb, w0t, w1t, ctr);
    }

    conv_phase<true ><<<NBLK, 256, 0, stream>>>(xb, nbr, w0t, b0, nullptr, hb, nullptr, ctr);
    conv_phase<false><<<NBLK, 256, 0, stream>>>(hb, nbr, w1t, b1, x, nullptr, out, ctr + NPH);
}

// Round 13
// 265.444 us; speedup vs baseline: 7.2069x; 2.9556x over previous
//
// round 12: revert to proven r5 flat kernel (passed @ 264us). Repack epilogue
// abandoned: 2 rounds failed identically; upside was only ~5us (r9 counters
// show inflation is eviction-timing, not store width; layer2 already full-line).
#include <hip/hip_runtime.h>
#include <hip/hip_bf16.h>

#define NV 300000
#define CH 32
#define KK 27
#define KP 28            // padded k-slices (slice 27 = zeros)

typedef __attribute__((ext_vector_type(8))) short bf16x8;
typedef __attribute__((ext_vector_type(4))) float f32x4;

// ws layout (bytes)
#define XB_OFF   0u
#define HB_OFF   19200128u            // (NV+1)*CH*2 = 19200064, padded
#define W0T_OFF  38400256u            // KP*CH*CH*2 = 57344
#define W1T_OFF  38457600u

__device__ __forceinline__ unsigned short f2b(float f) {
    unsigned int u = __builtin_bit_cast(unsigned int, f);
    unsigned int r = (u + 0x7FFFu + ((u >> 16) & 1u)) >> 16;
    return (unsigned short)r;
}

// --- prep: x -> bf16 (+pad row), zero h pad row, weights -> [k][d][c] bf16 (28 slices)
__global__ __launch_bounds__(256) void prep_kernel(
    const float* __restrict__ x,
    const float* __restrict__ w0,
    const float* __restrict__ w1,
    unsigned short* __restrict__ xb,
    unsigned short* __restrict__ hb,
    unsigned short* __restrict__ w0t,
    unsigned short* __restrict__ w1t)
{
    const int NX = NV * CH / 8;  // 1,200,000
    int tid = blockIdx.x * blockDim.x + threadIdx.x;
    if (tid < NX) {
        int base = tid * 8;
        const float4* p = reinterpret_cast<const float4*>(x + base);
        float4 a = p[0], b = p[1];
        union { unsigned short u[8]; bf16x8 v; } pk;
        pk.u[0] = f2b(a.x); pk.u[1] = f2b(a.y); pk.u[2] = f2b(a.z); pk.u[3] = f2b(a.w);
        pk.u[4] = f2b(b.x); pk.u[5] = f2b(b.y); pk.u[6] = f2b(b.z); pk.u[7] = f2b(b.w);
        *reinterpret_cast<bf16x8*>(xb + base) = pk.v;
        return;
    }
    int t = tid - NX;
    if (t < 4) {
        union { unsigned short u[8]; bf16x8 v; } z;
        for (int j = 0; j < 8; ++j) z.u[j] = 0;
        *reinterpret_cast<bf16x8*>(xb + NV * CH + t * 8) = z.v;
        return;
    }
    t -= 4;
    if (t < 4) {
        union { unsigned short u[8]; bf16x8 v; } z;
        for (int j = 0; j < 8; ++j) z.u[j] = 0;
        *reinterpret_cast<bf16x8*>(hb + NV * CH + t * 8) = z.v;
        return;
    }
    t -= 4;
    const int WELEM = KP * CH * CH;  // 28672
    if (t < 2 * WELEM) {
        int which = t >= WELEM;
        int e = t - which * WELEM;
        int k = e >> 10;
        int rem = e & 1023;
        int d = rem >> 5;
        int c = rem & 31;
        unsigned short* o = which ? w1t : w0t;
        if (k == KK) {
            o[e] = 0;
        } else {
            const float* w = which ? w1 : w0;
            o[e] = f2b(w[k * 1024 + c * 32 + d]);
        }
    }
}

// --- conv layer: 32 output rows per wave (2 tiles), batched k-loop, mfma 16x16x32 bf16
template <bool FIRST>
__global__ __launch_bounds__(256) void conv_kernel(
    const unsigned short* __restrict__ in_b,  // (NV+1)*CH bf16
    const int* __restrict__ nbr,              // KK*NV
    const unsigned short* __restrict__ wt,    // KP*CH*CH bf16, [k][d][c], slice 27 = 0
    const float* __restrict__ bias,           // CH
    const float* __restrict__ xres,           // NV*CH f32 (layer2) or null
    unsigned short* __restrict__ out_b,       // layer1 out (bf16)
    float* __restrict__ out_f)                // layer2 out (f32)
{
    const int wave = (blockIdx.x * blockDim.x + threadIdx.x) >> 6;
    if (wave >= NV / 32) return;   // 9375 waves, exact
    const int lane = threadIdx.x & 63;
    const int r = lane & 15;
    const int g = lane >> 4;
    const int row0 = wave * 32;
    const int i0 = row0 + r;
    const int i1 = row0 + 16 + r;

    f32x4 acc00 = {0.f, 0.f, 0.f, 0.f};
    f32x4 acc01 = {0.f, 0.f, 0.f, 0.f};
    f32x4 acc10 = {0.f, 0.f, 0.f, 0.f};
    f32x4 acc11 = {0.f, 0.f, 0.f, 0.f};

    const unsigned short* wt_r0 = wt + r * CH + g * 8;
    const unsigned short* wt_r1 = wt + (r + 16) * CH + g * 8;

#pragma unroll
    for (int kb = 0; kb < KP; kb += 4) {
        int idx0[4], idx1[4];
#pragma unroll
        for (int j = 0; j < 4; ++j) {
            int kk = kb + j;
            int ks = kk < KK ? kk : KK - 1;   // k=27 reuses 26 (B slice is zero)
            idx0[j] = nbr[ks * NV + i0];
            idx1[j] = nbr[ks * NV + i1];
        }
        bf16x8 a0[4], a1[4];
#pragma unroll
        for (int j = 0; j < 4; ++j) {
            a0[j] = *reinterpret_cast<const bf16x8*>(in_b + idx0[j] * CH + g * 8);
            a1[j] = *reinterpret_cast<const bf16x8*>(in_b + idx1[j] * CH + g * 8);
        }
#pragma unroll
        for (int j = 0; j < 4; ++j) {
            int kk = kb + j;
            bf16x8 b0 = *reinterpret_cast<const bf16x8*>(wt_r0 + kk * 1024);
            bf16x8 b1 = *reinterpret_cast<const bf16x8*>(wt_r1 + kk * 1024);
            acc00 = __builtin_amdgcn_mfma_f32_16x16x32_bf16(a0[j], b0, acc00, 0, 0, 0);
            acc10 = __builtin_amdgcn_mfma_f32_16x16x32_bf16(a1[j], b0, acc10, 0, 0, 0);
            acc01 = __builtin_amdgcn_mfma_f32_16x16x32_bf16(a0[j], b1, acc01, 0, 0, 0);
            acc11 = __builtin_amdgcn_mfma_f32_16x16x32_bf16(a1[j], b1, acc11, 0, 0, 0);
        }
    }

    const float bs0 = bias[r];
    const float bs1 = bias[r + 16];
#pragma unroll
    for (int j = 0; j < 4; ++j) {
        int ra = row0 + g * 4 + j;        // tile0 row
        int rb = ra + 16;                 // tile1 row
        float v00 = acc00[j] + bs0;       // (ra, r)
        float v01 = acc01[j] + bs1;       // (ra, r+16)
        float v10 = acc10[j] + bs0;       // (rb, r)
        float v11 = acc11[j] + bs1;       // (rb, r+16)
        if (FIRST) {
            out_b[ra * CH + r]      = f2b(fmaxf(v00, 0.f));
            out_b[ra * CH + r + 16] = f2b(fmaxf(v01, 0.f));
            out_b[rb * CH + r]      = f2b(fmaxf(v10, 0.f));
            out_b[rb * CH + r + 16] = f2b(fmaxf(v11, 0.f));
        } else {
            out_f[ra * CH + r]      = v00 + xres[ra * CH + r];
            out_f[ra * CH + r + 16] = v01 + xres[ra * CH + r + 16];
            out_f[rb * CH + r]      = v10 + xres[rb * CH + r];
            out_f[rb * CH + r + 16] = v11 + xres[rb * CH + r + 16];
        }
    }
}

extern "C" void kernel_launch(void* const* d_in, const int* in_sizes, int n_in,
                              void* d_out, int out_size, void* d_ws, size_t ws_size,
                              hipStream_t stream) {
    const float* x   = (const float*)d_in[0];
    const int* nbr   = (const int*)d_in[1];
    const float* w0  = (const float*)d_in[2];
    const float* b0  = (const float*)d_in[3];
    const float* w1  = (const float*)d_in[4];
    const float* b1  = (const float*)d_in[5];
    float* out = (float*)d_out;

    char* ws = (char*)d_ws;
    unsigned short* xb  = (unsigned short*)(ws + XB_OFF);
    unsigned short* hb  = (unsigned short*)(ws + HB_OFF);
    unsigned short* w0t = (unsigned short*)(ws + W0T_OFF);
    unsigned short* w1t = (unsigned short*)(ws + W1T_OFF);

    // prep
    {
        int total = NV * CH / 8 + 8 + 2 * KP * CH * CH;  // 1,257,352
        int blocks = (total + 255) / 256;
        prep_kernel<<<blocks, 256, 0, stream>>>(x, w0, w1, xb, hb, w0t, w1t);
    }
    // conv layers: one wave per 32 rows
    int threads = (NV / 32) * 64;        // 600,000
    int blocks = (threads + 255) / 256;  // 2344
    conv_kernel<true><<<blocks, 256, 0, stream>>>(xb, nbr, w0t, b0, nullptr, hb, nullptr);
    conv_kernel<false><<<blocks, 256, 0, stream>>>(hb, nbr, w1t, b1, x, nullptr, out);
}